// Round 4
// baseline (6866.779 us; speedup 1.0000x reference)
//
#include <hip/hip_runtime.h>

#define UNITS   114
#define SDIM    64
#define ACT     18
#define TSTEPS  64

// Globally-balanced edge chunking:
//   rec edges: inter->cmd 512 + cmd->cmd <=32 + cmd->motor 144 = <=688 total
//              -> NRS = ceil(704/64) = 11 slots/lane (vs 24 in the class-split
//              scheme; sigmoid count is the bottleneck at ~16 issue-cyc/trans)
//   sensory:   exactly 512 edges -> NSS = 8 slots/lane, zero padding
#define NRS   11
#define NSS   8
#define E_CAP (64 * NRS)   // 704
#define S_CAP (64 * NSS)   // 512

#define LOG2E 1.4426950408889634f
#define EPS   1e-8f

__device__ __forceinline__ float bperm(int addr, float v) {
  return __int_as_float(__builtin_amdgcn_ds_bpermute(addr, __float_as_int(v)));
}
// sigmoid((x-mu)*sigma) = rcp(1 + exp2(msl + x*nsgl)), nsgl = -sigma*log2e
__device__ __forceinline__ float sigm(float msl, float nsgl, float x) {
  return __builtin_amdgcn_rcpf(1.f + __builtin_amdgcn_exp2f(fmaf(x, nsgl, msl)));
}
__device__ __forceinline__ void lds_add(float* p, float v) {
  __hip_atomic_fetch_add(p, v, __ATOMIC_RELAXED, __HIP_MEMORY_SCOPE_WORKGROUP);
}
// Wave-internal LDS phase separator: compiler-only ordering (no instructions).
// HW executes a wave's LDS ops in program order (FIFO), so no s_barrier and no
// lgkmcnt(0) drain is needed for cross-lane LDS RAW within one wave.
__device__ __forceinline__ void wsync() {
  __builtin_amdgcn_fence(__ATOMIC_ACQ_REL, "wavefront");
  __builtin_amdgcn_wave_barrier();
}

// ---------------------------------------------------------------------------
// Build: post-major sorted edge lists, chunked 11 (rec) / 8 (sens) per lane.
// Edge record: (nsgl, msl, wn=w*erev, wd=w) + packed (pre | acc<<8).
// Pads: params all-zero -> sigma=0.5, wn=wd=0 -> contributes exactly 0.
// ---------------------------------------------------------------------------
__global__ __launch_bounds__(64) void build_tables(
    const float* __restrict__ w,  const float* __restrict__ mu,
    const float* __restrict__ sigma, const float* __restrict__ erev,
    const float* __restrict__ mask,
    const float* __restrict__ sw, const float* __restrict__ smu,
    const float* __restrict__ ssg, const float* __restrict__ serev,
    const float* __restrict__ smask,
    float4* __restrict__ recP, int* __restrict__ recA,
    float4* __restrict__ senP, int* __restrict__ senA)
{
  const int l = threadIdx.x;
  __shared__ float4 eP[E_CAP];
  __shared__ int    eIX[E_CAP];
  __shared__ int    cnt[64], off[65];

  // ---------------- recurrent: lane j<50 owns post-unit j ----------------
  int pres[40]; int D = 0;
  if (l < 50) {
    for (int base = 18; base < 114; base += 16) {
      float mv[16];
#pragma unroll
      for (int q = 0; q < 16; ++q) mv[q] = mask[(base + q) * UNITS + l];
#pragma unroll
      for (int q = 0; q < 16; ++q)
        if (mv[q] != 0.f && D < 40) pres[D++] = base + q;
    }
  }
  cnt[l] = (l < 50) ? D : 0;
  __syncthreads();
  if (l == 0) { int a = 0; for (int j = 0; j < 64; ++j) { off[j] = a; a += cnt[j]; } off[64] = a; }
  __syncthreads();
  {
    const int E = off[64];
    if (l < 50) {
      int o = off[l];
      for (int e = 0; e < D; ++e) {
        const int p = pres[e], idx = p * UNITS + l;
        const float sg = sigma[idx];
        eP[o + e]  = make_float4(-sg * LOG2E, mu[idx] * sg * LOG2E,
                                 w[idx] * erev[idx], w[idx]);
        eIX[o + e] = p | (l << 8);          // pre unit | accumulator idx (=post)
      }
    }
    for (int g = E + l; g < E_CAP; g += 64) { eP[g] = make_float4(0.f,0.f,0.f,0.f); eIX[g] = 0; }
  }
  __syncthreads();
#pragma unroll
  for (int s = 0; s < NRS; ++s) {           // lane-contiguous chunks
    const int g = l * NRS + s;
    recP[s * 64 + l] = eP[g]; recA[s * 64 + l] = eIX[g];
  }
  __syncthreads();

  // ---------------- sensory: lane l owns post inter-unit 50+l ----------------
  D = 0;
  {
    const int col = 50 + l;
    for (int base = 0; base < 64; base += 16) {
      float mv[16];
#pragma unroll
      for (int q = 0; q < 16; ++q) mv[q] = smask[(base + q) * UNITS + col];
#pragma unroll
      for (int q = 0; q < 16; ++q)
        if (mv[q] != 0.f && D < 40) pres[D++] = base + q;
    }
  }
  cnt[l] = D;
  __syncthreads();
  if (l == 0) { int a = 0; for (int j = 0; j < 64; ++j) { off[j] = a; a += cnt[j]; } off[64] = a; }
  __syncthreads();
  {
    const int E = off[64];                   // == 512 for this wiring
    {
      int o = off[l];
      const int col = 50 + l;
      for (int e = 0; e < D; ++e) {
        const int p = pres[e], idx = p * UNITS + col;
        const float sg = ssg[idx];
        eP[o + e]  = make_float4(-sg * LOG2E, smu[idx] * sg * LOG2E,
                                 sw[idx] * serev[idx], sw[idx]);
        eIX[o + e] = p | (l << 8);          // pre obs-dim | acc idx (=inter-50)
      }
    }
    for (int g = E + l; g < S_CAP; g += 64) { eP[g] = make_float4(0.f,0.f,0.f,0.f); eIX[g] = 0; }
  }
  __syncthreads();
#pragma unroll
  for (int s = 0; s < NSS; ++s) {
    const int g = l * NSS + s;
    senP[s * 64 + l] = eP[g]; senA[s * 64 + l] = eIX[g];
  }
}

// ---------------------------------------------------------------------------
// One wave per batch element. Unit layout: vA = unit l (motor 0..17, cmd
// 18..49, inter 50..63); vB = unit 64+l (inter, l<50). Full state mirrored in
// wave-private LDS; slot gathers are ds_read, partial-sum scatter is
// ds_add_f32 (same-wave FIFO order -> zero barriers in the recurrence).
// ---------------------------------------------------------------------------
__global__ __launch_bounds__(64, 2) void ltc_run(
    const float* __restrict__ obs,     const float* __restrict__ hidden,
    const float* __restrict__ input_w, const float* __restrict__ input_b,
    const float* __restrict__ gleak,   const float* __restrict__ vleak,
    const float* __restrict__ cm,
    const float* __restrict__ q_w1, const float* __restrict__ q_b1,
    const float* __restrict__ q_w2, const float* __restrict__ q_b2,
    const float4* __restrict__ recP, const int* __restrict__ recA,
    const float4* __restrict__ senP, const int* __restrict__ senA,
    float* __restrict__ out, int B)
{
  const int l = threadIdx.x;
  const int b = blockIdx.x;

  __shared__ float  mirror[128];     // units 0..113 (+pad)
  __shared__ float2 recAcc[64];      // (num,den) for post units 0..49 (+pad)
  __shared__ float2 sensAcc[64];     // (num,den) for inter units 50..113

  float4 rp[NRS]; int rpre[NRS], racc[NRS];
#pragma unroll
  for (int s = 0; s < NRS; ++s) {
    rp[s] = recP[s * 64 + l];
    const int ix = recA[s * 64 + l];
    rpre[s] = ix & 255; racc[s] = ix >> 8;
  }
  float4 sp[NSS]; int sba[NSS], sacc[NSS];
#pragma unroll
  for (int s = 0; s < NSS; ++s) {
    sp[s] = senP[s * 64 + l];
    const int ix = senA[s * 64 + l];
    sba[s] = (ix & 255) << 2; sacc[s] = ix >> 8;
  }

  // unit parameters: vA unit = l; owned inter unit iu (for the 1-fma update)
  const float cmtA = cm[l] * 6.f, glA = gleak[l], glvA = glA * vleak[l];
  const int   iu   = (l < 50) ? 64 + l : l;
  const float cmtI = cm[iu] * 6.f, glI = gleak[iu], glvI = glI * vleak[iu];
  const float denI0 = cmtI + glI + EPS;
  const int   accI  = iu - 50;

  float vA = hidden[(size_t)b * UNITS + l];
  float vB = (l < 50) ? hidden[(size_t)b * UNITS + 64 + l] : 0.f;
  mirror[l] = vA; mirror[64 + l] = vB;

  const float iw = input_w[l], ibv = input_b[l];
  const float* ob = obs + (size_t)b * (TSTEPS * SDIM) + l;
  float xr = ob[0];
  wsync();

  for (int t = 0; t < TSTEPS; ++t) {
    const float xi = xr * iw + ibv;            // lane l holds obs dim l
    if (t + 1 < TSTEPS) xr = ob[(t + 1) * SDIM];

    // ---- sensory -> inter (once per step) ----
    sensAcc[l] = make_float2(0.f, 0.f);
    wsync();
#pragma unroll
    for (int s = 0; s < NSS; ++s) {
      const float sg = sigm(sp[s].y, sp[s].x, bperm(sba[s], xi));
      lds_add(&sensAcc[sacc[s]].x, sg * sp[s].z);
      lds_add(&sensAcc[sacc[s]].y, sg * sp[s].w);
    }
    wsync();
    const float2 sv = sensAcc[accI];
    const float rdI = __builtin_amdgcn_rcpf(denI0 + sv.y);
    const float aI  = cmtI * rdI;
    const float bI  = (glvI + sv.x) * rdI;

    // ---- 6 ODE unfolds ----
#pragma unroll 1
    for (int u = 0; u < 6; ++u) {
      recAcc[l] = make_float2(0.f, 0.f);
      wsync();
#pragma unroll
      for (int s = 0; s < NRS; ++s) {
        const float sg = sigm(rp[s].y, rp[s].x, mirror[rpre[s]]);
        lds_add(&recAcc[racc[s]].x, sg * rp[s].z);
        lds_add(&recAcc[racc[s]].y, sg * rp[s].w);
      }
      wsync();
      const float2 rv = recAcc[l];
      const float vrec = (fmaf(cmtA, vA, glvA) + rv.x) *
                         __builtin_amdgcn_rcpf(cmtA + glA + rv.y + EPS);
      const float vIo  = fmaf(aI, (l < 50) ? vB : vA, bI);
      vA = (l < 50) ? vrec : vIo;
      vB = (l < 50) ? vIo : 0.f;
      mirror[l] = vA; mirror[64 + l] = vB;
      wsync();
    }
  }

  // ---- outputs: h then Q head (mirror holds final h) ----
  float* __restrict__ outH = out + (size_t)B * ACT;
  outH[(size_t)b * UNITS + l] = vA;
  if (l < 50) outH[(size_t)b * UNITS + 64 + l] = vB;

  const bool h2v = l < 50;
  const int  j2  = h2v ? 64 + l : l;
  float h1 = q_b1[l], h2 = q_b1[j2];
  for (int i = 0; i < UNITS; ++i) {
    const float hv = mirror[i];
    h1 = fmaf(hv, q_w1[i * UNITS + l],  h1);
    h2 = fmaf(hv, q_w1[i * UNITS + j2], h2);
  }
  h1 = fmaxf(h1, 0.f); h2 = fmaxf(h2, 0.f);
  wsync();
  mirror[l] = h1;
  if (h2v) mirror[64 + l] = h2;
  wsync();

  if (l < ACT) {
    float q = q_b2[l];
    for (int i = 0; i < UNITS; ++i) q = fmaf(mirror[i], q_w2[i * ACT + l], q);
    out[(size_t)b * ACT + l] = q;
  }
}

extern "C" void kernel_launch(void* const* d_in, const int* in_sizes, int n_in,
                              void* d_out, int out_size, void* d_ws, size_t ws_size,
                              hipStream_t stream)
{
  const float* obs           = (const float*)d_in[0];
  const float* hidden        = (const float*)d_in[1];
  const float* input_w       = (const float*)d_in[2];
  const float* input_b       = (const float*)d_in[3];
  const float* sensory_w     = (const float*)d_in[4];
  const float* sensory_mu    = (const float*)d_in[5];
  const float* sensory_sigma = (const float*)d_in[6];
  const float* sensory_erev  = (const float*)d_in[7];
  const float* sensory_mask  = (const float*)d_in[8];
  const float* w             = (const float*)d_in[9];
  const float* mu            = (const float*)d_in[10];
  const float* sigma         = (const float*)d_in[11];
  const float* erev          = (const float*)d_in[12];
  const float* mask          = (const float*)d_in[13];
  const float* gleak         = (const float*)d_in[14];
  const float* vleak         = (const float*)d_in[15];
  const float* cm            = (const float*)d_in[16];
  const float* q_w1          = (const float*)d_in[17];
  const float* q_b1          = (const float*)d_in[18];
  const float* q_w2          = (const float*)d_in[19];
  const float* q_b2          = (const float*)d_in[20];

  char* ws = (char*)d_ws;
  float4* recP = (float4*)(ws);            // 11*64*16 = 11264
  int*    recA = (int*)   (ws + 11264);    // 11*64*4  = 2816  -> 14080
  float4* senP = (float4*)(ws + 14080);    // 8*64*16  = 8192  -> 22272
  int*    senA = (int*)   (ws + 22272);    // 8*64*4   = 2048  -> 24320

  build_tables<<<1, 64, 0, stream>>>(
      w, mu, sigma, erev, mask,
      sensory_w, sensory_mu, sensory_sigma, sensory_erev, sensory_mask,
      recP, recA, senP, senA);

  const int B = in_sizes[0] / (TSTEPS * SDIM);
  ltc_run<<<B, 64, 0, stream>>>(
      obs, hidden, input_w, input_b, gleak, vleak, cm,
      q_w1, q_b1, q_w2, q_b2,
      recP, recA, senP, senA,
      (float*)d_out, B);
}

// Round 5
// 1275.779 us; speedup vs baseline: 5.3824x; 5.3824x over previous
//
#include <hip/hip_runtime.h>

#define UNITS   114
#define SDIM    64
#define ACT     18
#define TSTEPS  64

// Globally-balanced bin-packed slots:
//   rec:     E <= 704 edges (proven R3), max in-degree <= 32 (proven R2).
//            C=13/lane, <=2 posts per lane, <=3 lanes per post (3*13 >= 32).
//   sensory: E == 512, max in-degree <= 20 (proven R2). C=9, 3*9 >= 20.
#define CR 13
#define CS 9
#define ER_CAP 704
#define MSTRIDE 24

#define LOG2E 1.4426950408889634f
#define EPS   1e-8f

__device__ __forceinline__ float bperm(int addr, float v) {
  return __int_as_float(__builtin_amdgcn_ds_bpermute(addr, __float_as_int(v)));
}
__device__ __forceinline__ float dperm(int addr, float v) {   // push: lane[addr>>2] <- v
  return __int_as_float(__builtin_amdgcn_ds_permute(addr, __float_as_int(v)));
}
// sigmoid((x-mu)*sigma) = rcp(1 + exp2(msl + x*nsgl))
__device__ __forceinline__ float sigm(float msl, float nsgl, float x) {
  return __builtin_amdgcn_rcpf(1.f + __builtin_amdgcn_exp2f(fmaf(x, nsgl, msl)));
}
// Wave-internal LDS phase separator (compiler fence + wave barrier, ~0 instr).
// HW FIFO-orders one wave's LDS ops; correctness of this pattern proven in R3.
__device__ __forceinline__ void wsync() {
  __builtin_amdgcn_fence(__ATOMIC_ACQ_REL, "wavefront");
  __builtin_amdgcn_wave_barrier();
}

__device__ __forceinline__ int canonLane(int u) { return (u >= 64) ? (u - 64) : u; }

// ---------------------------------------------------------------------------
// Placement (thread 0): deal posts (sorted, contiguous edges) into lanes.
// Guarantees: <=2 posts/lane, <=3 lanes/post, owner = lane where post starts.
// ---------------------------------------------------------------------------
__device__ void placePosts(int nPosts, int C, const int* off,
    short* eLane, short* eSlot, short* eRole,
    int* contIdx, int* contOwn, int* splitRole, int* split2, int* ownP)
{
  for (int i = 0; i < 64; ++i) {
    contIdx[i] = 0; contOwn[i] = 0; splitRole[i] = -1; split2[i] = 0;
    ownP[2*i] = -1; ownP[2*i + 1] = -1;
  }
  int lam = 0, f = 0, pc = 0;
  for (int p = 0; p < nPosts; ++p) {
    const int d = off[p+1] - off[p];
    if (pc == 2 || f == C || d > 3*C - f) { ++lam; f = 0; pc = 0; }
    if (lam > 63) lam = 63;                       // defensive (loud failure)
    const int owner = lam, role = pc;
    ownP[2*lam + role] = p; ++pc;
    int e = off[p];
    int take = d < (C - f) ? d : (C - f);
    for (int k = 0; k < take; ++k) { eLane[e+k]=lam; eSlot[e+k]=f+k; eRole[e+k]=role; }
    f += take; e += take; int rem = d - take;
    if (rem > 0) {
      splitRole[owner] = role; split2[owner] = (rem > C) ? 1 : 0;
      ++lam; if (lam > 63) lam = 63;
      contIdx[lam] = 1; contOwn[lam] = owner; pc = 1;
      int t2 = rem < C ? rem : C;
      for (int k = 0; k < t2; ++k) { eLane[e+k]=lam; eSlot[e+k]=k; eRole[e+k]=0; }
      f = t2; e += t2; rem -= t2;
      if (rem > 0) {
        ++lam; if (lam > 63) lam = 63;
        contIdx[lam] = 2; contOwn[lam] = owner; pc = 1;
        for (int k = 0; k < rem; ++k) { eLane[e+k]=lam; eSlot[e+k]=k; eRole[e+k]=0; }
        f = rem;
      }
    }
  }
}

// Assign dummy pushers distinct dests among lanes receiving no real push.
__device__ void fillDests(int* dst) {
  bool recv[64];
  for (int i = 0; i < 64; ++i) recv[i] = false;
  for (int i = 0; i < 64; ++i) if (dst[i] >= 0) recv[dst[i]] = true;
  int q = 0;
  for (int i = 0; i < 64; ++i)
    if (dst[i] < 0) { while (q < 63 && recv[q]) ++q; dst[i] = q; ++q; }
}

// ---------------------------------------------------------------------------
// Build kernel: sorted edge lists -> bin-packed slot tables + per-lane meta.
// Slot record: P4 = (nsgl, msl, wnA, wdA), P2 = (wnB, wdB), Ad = gather addr.
// ---------------------------------------------------------------------------
__global__ __launch_bounds__(64) void build_all(
    const float* __restrict__ w,  const float* __restrict__ mu,
    const float* __restrict__ sigma, const float* __restrict__ erev,
    const float* __restrict__ mask,
    const float* __restrict__ sw, const float* __restrict__ smu,
    const float* __restrict__ ssg, const float* __restrict__ serev,
    const float* __restrict__ smask,
    float4* __restrict__ recP4, float2* __restrict__ recP2, int* __restrict__ recAd,
    float4* __restrict__ senP4, float2* __restrict__ senP2, int* __restrict__ senAd,
    int* __restrict__ meta)
{
  const int l = threadIdx.x;
  __shared__ short ePre[ER_CAP], ePost[ER_CAP], eLane[ER_CAP], eSlot[ER_CAP], eRole[ER_CAP];
  __shared__ int deg[64], off[65];
  __shared__ int contIdx[64], contOwn[64], splitRole[64], split2[64], ownP[128];
  __shared__ int LM[64 * MSTRIDE];
  __shared__ int dstA[64], dstB[64];

  // ================= recurrent (posts 0..49, pres 18..113) =================
  int d = 0;
  if (l < 50) for (int i = 18; i < UNITS; ++i) d += (mask[i*UNITS + l] != 0.f) ? 1 : 0;
  deg[l] = (l < 50) ? d : 0;
  __syncthreads();
  if (l == 0) { int a = 0; for (int j = 0; j < 64; ++j) { off[j] = a; a += deg[j]; } off[64] = a; }
  __syncthreads();
  if (l < 50) {
    int o = off[l];
    for (int i = 18; i < UNITS; ++i)
      if (mask[i*UNITS + l] != 0.f) { ePre[o] = i; ePost[o] = l; ++o; }
  }
  __syncthreads();
  if (l == 0) {
    placePosts(50, CR, off, eLane, eSlot, eRole, contIdx, contOwn, splitRole, split2, ownP);
    for (int i = 0; i < 64; ++i) dstA[i] = (contIdx[i] == 1) ? contOwn[i] : -1;
    for (int i = 0; i < 64; ++i) dstB[i] = (contIdx[i] == 2) ? contOwn[i] : -1;
    fillDests(dstA); fillDests(dstB);
    for (int i = 0; i < 64; ++i) {
      int* M = LM + i * MSTRIDE;
      M[0] = dstA[i] * 4; M[1] = dstB[i] * 4;
      float s1A = (splitRole[i] == 0) ? 1.f : 0.f, s1B = (splitRole[i] == 1) ? 1.f : 0.f;
      M[2] = __float_as_int(s1A); M[3] = __float_as_int(s1B);
      M[4] = __float_as_int(s1A * (split2[i] ? 1.f : 0.f));
      M[5] = __float_as_int(s1B * (split2[i] ? 1.f : 0.f));
      const int uA = ownP[2*i], uB = ownP[2*i + 1];       // rec: post idx == unit
      M[6] = ((uA >= 0) ? uA : 128 + i) * 4;              // write addr (scratch if none)
      M[7] = ((uB >= 0) ? uB : 192 + i) * 4;
      M[8] = (uA >= 0) ? uA : 0;
      M[9] = (uB >= 0) ? uB : 0;
    }
  }
  __syncthreads();
  for (int t = l; t < CR*64; t += 64) {
    recP4[t] = make_float4(0.f,0.f,0.f,0.f); recP2[t] = make_float2(0.f,0.f); recAd[t] = 0;
  }
  {
    const int E = off[64];
    for (int e = l; e < E; e += 64) {
      const int pre = ePre[e], post = ePost[e];
      const int lam = eLane[e], s = eSlot[e], role = eRole[e];
      const int idx = pre * UNITS + post;
      const float sg = sigma[idx];
      const float nsgl = -sg * LOG2E, msl = mu[idx] * sg * LOG2E;
      const float wd = w[idx], wn = wd * erev[idx];
      const int t = s * 64 + lam;
      recP4[t] = make_float4(nsgl, msl, role ? 0.f : wn, role ? 0.f : wd);
      recP2[t] = role ? make_float2(wn, wd) : make_float2(0.f, 0.f);
      recAd[t] = pre * 4;                                 // mirror byte addr
    }
  }
  __syncthreads();

  // ================= sensory (posts 50..113, pres 0..63) =================
  d = 0;
  { const int col = 50 + l; for (int i = 0; i < SDIM; ++i) d += (smask[i*UNITS + col] != 0.f) ? 1 : 0; }
  deg[l] = d;
  __syncthreads();
  if (l == 0) { int a = 0; for (int j = 0; j < 64; ++j) { off[j] = a; a += deg[j]; } off[64] = a; }
  __syncthreads();
  {
    int o = off[l]; const int col = 50 + l;
    for (int i = 0; i < SDIM; ++i)
      if (smask[i*UNITS + col] != 0.f) { ePre[o] = i; ePost[o] = col; ++o; }
  }
  __syncthreads();
  if (l == 0) {
    placePosts(64, CS, off, eLane, eSlot, eRole, contIdx, contOwn, splitRole, split2, ownP);
    for (int i = 0; i < 64; ++i) dstA[i] = (contIdx[i] == 1) ? contOwn[i] : -1;
    for (int i = 0; i < 64; ++i) dstB[i] = (contIdx[i] == 2) ? contOwn[i] : -1;
    fillDests(dstA); fillDests(dstB);
    for (int i = 0; i < 64; ++i) {
      int* M = LM + i * MSTRIDE;
      M[10] = dstA[i] * 4; M[11] = dstB[i] * 4;
      float s1A = (splitRole[i] == 0) ? 1.f : 0.f, s1B = (splitRole[i] == 1) ? 1.f : 0.f;
      M[12] = __float_as_int(s1A); M[13] = __float_as_int(s1B);
      M[14] = __float_as_int(s1A * (split2[i] ? 1.f : 0.f));
      M[15] = __float_as_int(s1B * (split2[i] ? 1.f : 0.f));
      const int pA = ownP[2*i], pB = ownP[2*i + 1];
      M[20] = (pA >= 0) ? 50 + pA : 0;
      M[21] = (pB >= 0) ? 50 + pB : 0;
    }
    // route rounds: owner -> canonical lane of its inter unit
    bool rcvA[64];
    for (int i = 0; i < 64; ++i) rcvA[i] = false;
    for (int i = 0; i < 64; ++i) { int p = ownP[2*i];   dstA[i] = (p >= 0) ? canonLane(50 + p) : -1; if (p >= 0) rcvA[dstA[i]] = true; }
    for (int i = 0; i < 64; ++i) { int p = ownP[2*i+1]; dstB[i] = (p >= 0) ? canonLane(50 + p) : -1; }
    for (int i = 0; i < 64; ++i) {
      LM[i*MSTRIDE + 18] = __float_as_int(rcvA[i] ? 1.f : 0.f);
      LM[i*MSTRIDE + 19] = __float_as_int(rcvA[i] ? 0.f : 1.f);
    }
    fillDests(dstA); fillDests(dstB);
    for (int i = 0; i < 64; ++i) { LM[i*MSTRIDE + 16] = dstA[i] * 4; LM[i*MSTRIDE + 17] = dstB[i] * 4; }
  }
  __syncthreads();
  for (int t = l; t < CS*64; t += 64) {
    senP4[t] = make_float4(0.f,0.f,0.f,0.f); senP2[t] = make_float2(0.f,0.f); senAd[t] = 0;
  }
  {
    const int E = off[64];
    for (int e = l; e < E; e += 64) {
      const int pre = ePre[e], post = ePost[e];
      const int lam = eLane[e], s = eSlot[e], role = eRole[e];
      const int idx = pre * UNITS + post;
      const float sg = ssg[idx];
      const float nsgl = -sg * LOG2E, msl = smu[idx] * sg * LOG2E;
      const float wd = sw[idx], wn = wd * serev[idx];
      const int t = s * 64 + lam;
      senP4[t] = make_float4(nsgl, msl, role ? 0.f : wn, role ? 0.f : wd);
      senP2[t] = role ? make_float2(wn, wd) : make_float2(0.f, 0.f);
      senAd[t] = pre * 4;                                 // bperm byte addr into xi
    }
  }
  __syncthreads();
  for (int k = l; k < 64 * MSTRIDE; k += 64) meta[k] = LM[k];
}

// ---------------------------------------------------------------------------
// Run kernel: one wave per batch element. State: owner registers + LDS mirror.
// Gathers: ds_read from mirror. Merges/routes: static ds_permute. No atomics,
// no s_barrier in the recurrence.
// ---------------------------------------------------------------------------
__global__ __launch_bounds__(64, 2) void ltc_run(
    const float* __restrict__ obs,     const float* __restrict__ hidden,
    const float* __restrict__ input_w, const float* __restrict__ input_b,
    const float* __restrict__ gleak,   const float* __restrict__ vleak,
    const float* __restrict__ cm,
    const float* __restrict__ q_w1, const float* __restrict__ q_b1,
    const float* __restrict__ q_w2, const float* __restrict__ q_b2,
    const float4* __restrict__ recP4, const float2* __restrict__ recP2,
    const int* __restrict__ recAd,
    const float4* __restrict__ senP4, const float2* __restrict__ senP2,
    const int* __restrict__ senAd,
    const int* __restrict__ meta, float* __restrict__ out, int B)
{
  const int l = threadIdx.x, b = blockIdx.x;
  __shared__ float mirror[256];   // [0..113] units, [128..255] scratch sinks
  char* mbase = (char*)mirror;

  float4 rp4[CR]; float2 rp2[CR]; int rad[CR];
#pragma unroll
  for (int s = 0; s < CR; ++s) { rp4[s] = recP4[s*64+l]; rp2[s] = recP2[s*64+l]; rad[s] = recAd[s*64+l]; }
  float4 sp4[CS]; float2 sp2[CS]; int sad[CS];
#pragma unroll
  for (int s = 0; s < CS; ++s) { sp4[s] = senP4[s*64+l]; sp2[s] = senP2[s*64+l]; sad[s] = senAd[s*64+l]; }

  const int* M = meta + l * MSTRIDE;
  const int   rPush1 = M[0], rPush2 = M[1];
  const float rS1A = __int_as_float(M[2]), rS1B = __int_as_float(M[3]);
  const float rS2A = __int_as_float(M[4]), rS2B = __int_as_float(M[5]);
  const int   rWrA = M[6], rWrB = M[7], rUA = M[8], rUB = M[9];
  const int   sPush1 = M[10], sPush2 = M[11];
  const float sS1A = __int_as_float(M[12]), sS1B = __int_as_float(M[13]);
  const float sS2A = __int_as_float(M[14]), sS2B = __int_as_float(M[15]);
  const int   sRtA = M[16], sRtB = M[17];
  const float sRndA = __int_as_float(M[18]), sRndB = __int_as_float(M[19]);
  const int   sUA = M[20], sUB = M[21];

  const float cmA  = cm[rUA]*6.f, glvA  = gleak[rUA]*vleak[rUA], cgA  = cm[rUA]*6.f + gleak[rUA] + EPS;
  const float cmB  = cm[rUB]*6.f, glvB  = gleak[rUB]*vleak[rUB], cgB  = cm[rUB]*6.f + gleak[rUB] + EPS;
  const float cmSA = cm[sUA]*6.f, glvSA = gleak[sUA]*vleak[sUA], cgSA = cm[sUA]*6.f + gleak[sUA] + EPS;
  const float cmSB = cm[sUB]*6.f, glvSB = gleak[sUB]*vleak[sUB], cgSB = cm[sUB]*6.f + gleak[sUB] + EPS;

  const int  iUnit = (l < 50) ? 64 + l : l;     // canonical inter unit of this lane
  const int  iWr   = iUnit * 4;
  float vIn = hidden[(size_t)b*UNITS + iUnit];
  float vPA = hidden[(size_t)b*UNITS + rUA];
  float vPB = hidden[(size_t)b*UNITS + rUB];

  mirror[l] = hidden[(size_t)b*UNITS + l];
  if (l < 50) mirror[64 + l] = hidden[(size_t)b*UNITS + 64 + l];

  const float iw = input_w[l], ibv = input_b[l];
  const float* ob = obs + (size_t)b*(TSTEPS*SDIM) + l;
  float xr = ob[0];

  for (int t = 0; t < TSTEPS; ++t) {
    const float xi = xr * iw + ibv;             // lane l holds obs dim l
    if (t + 1 < TSTEPS) xr = ob[(t + 1) * SDIM];

    // ---- sensory accumulation (balanced slots), merge, (aI,bI) route ----
    float snA=0.f, sdA=0.f, snB=0.f, sdB=0.f;
#pragma unroll
    for (int s = 0; s < CS; ++s) {
      const float sg = sigm(sp4[s].y, sp4[s].x, bperm(sad[s], xi));
      snA = fmaf(sp4[s].z, sg, snA); sdA = fmaf(sp4[s].w, sg, sdA);
      snB = fmaf(sp2[s].x, sg, snB); sdB = fmaf(sp2[s].y, sg, sdB);
    }
    { const float rn = dperm(sPush1, snA), rd = dperm(sPush1, sdA);
      snA = fmaf(sS1A, rn, snA); sdA = fmaf(sS1A, rd, sdA);
      snB = fmaf(sS1B, rn, snB); sdB = fmaf(sS1B, rd, sdB); }
    { const float rn = dperm(sPush2, snA), rd = dperm(sPush2, sdA);
      snA = fmaf(sS2A, rn, snA); sdA = fmaf(sS2A, rd, sdA);
      snB = fmaf(sS2B, rn, snB); sdB = fmaf(sS2B, rd, sdB); }
    const float rdA_ = __builtin_amdgcn_rcpf(cgSA + sdA);
    const float aA_ = cmSA * rdA_, bA_ = (glvSA + snA) * rdA_;
    const float rdB_ = __builtin_amdgcn_rcpf(cgSB + sdB);
    const float aB_ = cmSB * rdB_, bB_ = (glvSB + snB) * rdB_;
    const float ra1 = dperm(sRtA, aA_), rb1 = dperm(sRtA, bA_);
    const float ra2 = dperm(sRtB, aB_), rb2 = dperm(sRtB, bB_);
    const float aI = sRndA * ra1 + sRndB * ra2;
    const float bI = sRndA * rb1 + sRndB * rb2;

    // ---- 6 ODE unfolds ----
#pragma unroll 1
    for (int u = 0; u < 6; ++u) {
      wsync();                                   // prev writes -> this unfold's reads
      float nA=0.f, dA=0.f, nB=0.f, dB=0.f;
#pragma unroll
      for (int s = 0; s < CR; ++s) {
        const float pv = *(const float*)(mbase + rad[s]);
        const float sg = sigm(rp4[s].y, rp4[s].x, pv);
        nA = fmaf(rp4[s].z, sg, nA); dA = fmaf(rp4[s].w, sg, dA);
        nB = fmaf(rp2[s].x, sg, nB); dB = fmaf(rp2[s].y, sg, dB);
      }
      { const float rn = dperm(rPush1, nA), rd = dperm(rPush1, dA);
        nA = fmaf(rS1A, rn, nA); dA = fmaf(rS1A, rd, dA);
        nB = fmaf(rS1B, rn, nB); dB = fmaf(rS1B, rd, dB); }
      { const float rn = dperm(rPush2, nA), rd = dperm(rPush2, dA);
        nA = fmaf(rS2A, rn, nA); dA = fmaf(rS2A, rd, dA);
        nB = fmaf(rS2B, rn, nB); dB = fmaf(rS2B, rd, dB); }
      vPA = (fmaf(cmA, vPA, glvA) + nA) * __builtin_amdgcn_rcpf(cgA + dA);
      vPB = (fmaf(cmB, vPB, glvB) + nB) * __builtin_amdgcn_rcpf(cgB + dB);
      vIn = fmaf(aI, vIn, bI);
      wsync();                                   // all reads done -> overwrite
      *(float*)(mbase + rWrA) = vPA;
      *(float*)(mbase + rWrB) = vPB;
      *(float*)(mbase + iWr)  = vIn;
    }
  }
  wsync();

  // ---- outputs: h then Q head ----
  float* __restrict__ outH = out + (size_t)B * ACT;
  outH[(size_t)b*UNITS + l] = mirror[l];
  if (l < 50) outH[(size_t)b*UNITS + 64 + l] = mirror[64 + l];

  const int j2 = (l < 50) ? 64 + l : l;
  float h1 = q_b1[l], h2 = q_b1[j2];
  for (int i = 0; i < UNITS; ++i) {
    const float hv = mirror[i];
    h1 = fmaf(hv, q_w1[i*UNITS + l],  h1);
    h2 = fmaf(hv, q_w1[i*UNITS + j2], h2);
  }
  h1 = fmaxf(h1, 0.f); h2 = fmaxf(h2, 0.f);
  wsync();
  mirror[l] = h1;
  if (l < 50) mirror[64 + l] = h2;
  wsync();
  if (l < ACT) {
    float q = q_b2[l];
    for (int i = 0; i < UNITS; ++i) q = fmaf(mirror[i], q_w2[i*ACT + l], q);
    out[(size_t)b*ACT + l] = q;
  }
}

extern "C" void kernel_launch(void* const* d_in, const int* in_sizes, int n_in,
                              void* d_out, int out_size, void* d_ws, size_t ws_size,
                              hipStream_t stream)
{
  const float* obs           = (const float*)d_in[0];
  const float* hidden        = (const float*)d_in[1];
  const float* input_w       = (const float*)d_in[2];
  const float* input_b       = (const float*)d_in[3];
  const float* sensory_w     = (const float*)d_in[4];
  const float* sensory_mu    = (const float*)d_in[5];
  const float* sensory_sigma = (const float*)d_in[6];
  const float* sensory_erev  = (const float*)d_in[7];
  const float* sensory_mask  = (const float*)d_in[8];
  const float* w             = (const float*)d_in[9];
  const float* mu            = (const float*)d_in[10];
  const float* sigma         = (const float*)d_in[11];
  const float* erev          = (const float*)d_in[12];
  const float* mask          = (const float*)d_in[13];
  const float* gleak         = (const float*)d_in[14];
  const float* vleak         = (const float*)d_in[15];
  const float* cm            = (const float*)d_in[16];
  const float* q_w1          = (const float*)d_in[17];
  const float* q_b1          = (const float*)d_in[18];
  const float* q_w2          = (const float*)d_in[19];
  const float* q_b2          = (const float*)d_in[20];

  char* ws = (char*)d_ws;
  float4* recP4 = (float4*)(ws);            // 13*64*16 = 13312
  float2* recP2 = (float2*)(ws + 13312);    // 13*64*8  = 6656  -> 19968
  int*    recAd = (int*)   (ws + 19968);    // 13*64*4  = 3328  -> 23296
  float4* senP4 = (float4*)(ws + 23296);    // 9*64*16  = 9216  -> 32512
  float2* senP2 = (float2*)(ws + 32512);    // 9*64*8   = 4608  -> 37120
  int*    senAd = (int*)   (ws + 37120);    // 9*64*4   = 2304  -> 39424
  int*    meta  = (int*)   (ws + 39424);    // 64*24*4  = 6144  -> 45568

  build_all<<<1, 64, 0, stream>>>(
      w, mu, sigma, erev, mask,
      sensory_w, sensory_mu, sensory_sigma, sensory_erev, sensory_mask,
      recP4, recP2, recAd, senP4, senP2, senAd, meta);

  const int B = in_sizes[0] / (TSTEPS * SDIM);
  ltc_run<<<B, 64, 0, stream>>>(
      obs, hidden, input_w, input_b, gleak, vleak, cm,
      q_w1, q_b1, q_w2, q_b2,
      recP4, recP2, recAd, senP4, senP2, senAd, meta,
      (float*)d_out, B);
}

// Round 6
// 404.258 us; speedup vs baseline: 16.9861x; 3.1559x over previous
//
#include <hip/hip_runtime.h>

#define UNITS   114
#define SDIM    64
#define ACT     18
#define TSTEPS  64

// Globally-balanced bin-packed slots (placement semantics identical to R4):
//   rec:     E <= 704 edges, max in-degree <= 32. C=13/lane, <=2 posts/lane,
//            <=3 lanes/post (3*13 >= 32).
//   sensory: E == 512, max in-degree <= 20. C=9, 3*9 >= 20.
#define CR 13
#define CS 9
#define ER_CAP 704
#define MSTRIDE 24

#define LOG2E 1.4426950408889634f
#define EPS   1e-8f

__device__ __forceinline__ float bperm(int addr, float v) {
  return __int_as_float(__builtin_amdgcn_ds_bpermute(addr, __float_as_int(v)));
}
__device__ __forceinline__ float dperm(int addr, float v) {   // push: lane[addr>>2] <- v
  return __int_as_float(__builtin_amdgcn_ds_permute(addr, __float_as_int(v)));
}
// sigmoid((x-mu)*sigma) = rcp(1 + exp2(msl + x*nsgl))
__device__ __forceinline__ float sigm(float msl, float nsgl, float x) {
  return __builtin_amdgcn_rcpf(1.f + __builtin_amdgcn_exp2f(fmaf(x, nsgl, msl)));
}
// Wave-internal LDS phase separator (compiler fence + wave barrier, ~0 instr).
__device__ __forceinline__ void wsync() {
  __builtin_amdgcn_fence(__ATOMIC_ACQ_REL, "wavefront");
  __builtin_amdgcn_wave_barrier();
}
__device__ __forceinline__ int canonLane(int u) { return (u >= 64) ? (u - 64) : u; }

// k-th set bit of a 64-bit mask (k 0-based), branch-light binary search.
__device__ __forceinline__ int kthSetBit(unsigned long long m, int k) {
  int pos = 0;
#pragma unroll
  for (int ww = 32; ww >= 1; ww >>= 1) {
    const unsigned long long lowMask = ((1ull << ww) - 1ull);
    const int c = __popcll(m & lowMask);
    if (k >= c) { k -= c; m >>= ww; pos += ww; }
  }
  return pos;
}

// ---------------------------------------------------------------------------
// Build: 2 independent blocks (0 = recurrent, 1 = sensory). Serial part is
// only the tiny per-post state machine; edge placement, dummy-dest fill
// (ballot + kth-set-bit), and meta are fully lane-parallel. No scratch arrays.
// ---------------------------------------------------------------------------
__global__ __launch_bounds__(64) void build_all(
    const float* __restrict__ w,  const float* __restrict__ mu,
    const float* __restrict__ sigma, const float* __restrict__ erev,
    const float* __restrict__ mask,
    const float* __restrict__ sw, const float* __restrict__ smu,
    const float* __restrict__ ssg, const float* __restrict__ serev,
    const float* __restrict__ smask,
    float4* __restrict__ recP4, float2* __restrict__ recP2, int* __restrict__ recAd,
    float4* __restrict__ senP4, float2* __restrict__ senP2, int* __restrict__ senAd,
    int* __restrict__ meta)
{
  const int l = threadIdx.x;
  __shared__ short ePre[ER_CAP], ePIdx[ER_CAP];
  __shared__ int deg[64], off[65];
  __shared__ int pLane[64], pF0[64], pRole[64];
  __shared__ int contIdx[64], contOwn[64], splitRole[64], split2[64], ownP[128];
  __shared__ int rcv[64];

  contIdx[l] = 0; contOwn[l] = 0; splitRole[l] = -1; split2[l] = 0;
  ownP[2*l] = -1; ownP[2*l+1] = -1;
  pLane[l] = 0; pF0[l] = 0; pRole[l] = 0;

  if (blockIdx.x == 0) {
    // ===================== recurrent (posts 0..49, pres 18..113) =====================
    int d = 0;
    if (l < 50) for (int i = 18; i < UNITS; ++i) d += (mask[i*UNITS + l] != 0.f) ? 1 : 0;
    deg[l] = (l < 50) ? d : 0;
    __syncthreads();
    if (l == 0) { int a = 0; for (int j = 0; j < 64; ++j) { off[j] = a; a += deg[j]; } off[64] = a; }
    __syncthreads();
    if (l < 50) {
      int o = off[l];
      for (int i = 18; i < UNITS; ++i)
        if (mask[i*UNITS + l] != 0.f) { ePre[o] = (short)i; ePIdx[o] = (short)l; ++o; }
    }
    if (l == 0) {                       // tiny serial state machine, 50 steps
      int lam = 0, f = 0, pc = 0;
      for (int p = 0; p < 50; ++p) {
        const int dd = deg[p];
        if (pc == 2 || f == CR || dd > 3*CR - f) { ++lam; f = 0; pc = 0; }
        if (lam > 63) lam = 63;
        pLane[p] = lam; pF0[p] = f; pRole[p] = pc;
        ownP[2*lam + pc] = p;
        const int owner = lam, role = pc; ++pc;
        const int take = dd < (CR - f) ? dd : (CR - f);
        f += take; int rem = dd - take;
        if (rem > 0) {
          splitRole[owner] = role; split2[owner] = (rem > CR) ? 1 : 0;
          ++lam; if (lam > 63) lam = 63; contIdx[lam] = 1; contOwn[lam] = owner; pc = 1;
          const int t2 = rem < CR ? rem : CR; f = t2; rem -= t2;
          if (rem > 0) { ++lam; if (lam > 63) lam = 63; contIdx[lam] = 2; contOwn[lam] = owner; pc = 1; f = rem; }
        }
      }
    }
    __syncthreads();
    // dummy-dest fill, parallel (receivers of real cont pushes are distinct owners)
    int dA = (contIdx[l] == 1) ? contOwn[l] : -1;
    int dB = (contIdx[l] == 2) ? contOwn[l] : -1;
    rcv[l] = 0; __syncthreads();
    if (dA >= 0) rcv[dA] = 1;
    __syncthreads();
    {
      const unsigned long long recvM = __ballot(rcv[l] != 0);
      const unsigned long long dumm  = __ballot(dA < 0);
      if (dA < 0) dA = kthSetBit(~recvM, __popcll(dumm & ((1ull << l) - 1ull)));
    }
    __syncthreads();
    rcv[l] = 0; __syncthreads();
    if (dB >= 0) rcv[dB] = 1;
    __syncthreads();
    {
      const unsigned long long recvM = __ballot(rcv[l] != 0);
      const unsigned long long dumm  = __ballot(dB < 0);
      if (dB < 0) dB = kthSetBit(~recvM, __popcll(dumm & ((1ull << l) - 1ull)));
    }
    // meta words 0..9 (parallel)
    {
      int* M = meta + l * MSTRIDE;
      M[0] = dA * 4; M[1] = dB * 4;
      const float s1A = (splitRole[l] == 0) ? 1.f : 0.f, s1B = (splitRole[l] == 1) ? 1.f : 0.f;
      M[2] = __float_as_int(s1A); M[3] = __float_as_int(s1B);
      const float s2 = split2[l] ? 1.f : 0.f;
      M[4] = __float_as_int(s1A * s2); M[5] = __float_as_int(s1B * s2);
      const int uA = ownP[2*l], uB = ownP[2*l+1];
      M[6] = ((uA >= 0) ? uA : 128 + l) * 4;
      M[7] = ((uB >= 0) ? uB : 192 + l) * 4;
      M[8] = (uA >= 0) ? uA : 0;
      M[9] = (uB >= 0) ? uB : 0;
    }
    // zero + fill rec tables (parallel closed-form placement reconstruction)
    for (int t = l; t < CR*64; t += 64) {
      recP4[t] = make_float4(0.f,0.f,0.f,0.f); recP2[t] = make_float2(0.f,0.f); recAd[t] = 0;
    }
    __syncthreads();
    {
      const int E = off[64];
      for (int e = l; e < E; e += 64) {
        const int pre = ePre[e], pj = ePIdx[e];
        const int r  = e - off[pj];
        const int dd = deg[pj], f0 = pF0[pj], role0 = pRole[pj];
        const int take = dd < (CR - f0) ? dd : (CR - f0);
        int lane = pLane[pj], slot, role;
        if (r < take)            { slot = f0 + r;        role = role0; }
        else if (r < take + CR)  { lane += 1; slot = r - take;      role = 0; }
        else                     { lane += 2; slot = r - take - CR; role = 0; }
        if (lane > 63) lane = 63;
        const int idx = pre * UNITS + pj;           // rec post unit == pj
        const float sg = sigma[idx];
        const float nsgl = -sg * LOG2E, msl = mu[idx] * sg * LOG2E;
        const float wd = w[idx], wn = wd * erev[idx];
        const int tt = slot * 64 + lane;
        recP4[tt] = make_float4(nsgl, msl, role ? 0.f : wn, role ? 0.f : wd);
        recP2[tt] = role ? make_float2(wn, wd) : make_float2(0.f, 0.f);
        recAd[tt] = pre * 4;
      }
    }
  } else {
    // ===================== sensory (posts 0..63 -> units 50..113, pres 0..63) =====================
    int d = 0;
    { const int col = 50 + l; for (int i = 0; i < SDIM; ++i) d += (smask[i*UNITS + col] != 0.f) ? 1 : 0; }
    deg[l] = d;
    __syncthreads();
    if (l == 0) { int a = 0; for (int j = 0; j < 64; ++j) { off[j] = a; a += deg[j]; } off[64] = a; }
    __syncthreads();
    {
      int o = off[l]; const int col = 50 + l;
      for (int i = 0; i < SDIM; ++i)
        if (smask[i*UNITS + col] != 0.f) { ePre[o] = (short)i; ePIdx[o] = (short)l; ++o; }
    }
    if (l == 0) {                       // serial state machine, 64 steps
      int lam = 0, f = 0, pc = 0;
      for (int p = 0; p < 64; ++p) {
        const int dd = deg[p];
        if (pc == 2 || f == CS || dd > 3*CS - f) { ++lam; f = 0; pc = 0; }
        if (lam > 63) lam = 63;
        pLane[p] = lam; pF0[p] = f; pRole[p] = pc;
        ownP[2*lam + pc] = p;
        const int owner = lam, role = pc; ++pc;
        const int take = dd < (CS - f) ? dd : (CS - f);
        f += take; int rem = dd - take;
        if (rem > 0) {
          splitRole[owner] = role; split2[owner] = (rem > CS) ? 1 : 0;
          ++lam; if (lam > 63) lam = 63; contIdx[lam] = 1; contOwn[lam] = owner; pc = 1;
          const int t2 = rem < CS ? rem : CS; f = t2; rem -= t2;
          if (rem > 0) { ++lam; if (lam > 63) lam = 63; contIdx[lam] = 2; contOwn[lam] = owner; pc = 1; f = rem; }
        }
      }
    }
    __syncthreads();
    // merge dummy-dest fill (parallel)
    int dA = (contIdx[l] == 1) ? contOwn[l] : -1;
    int dB = (contIdx[l] == 2) ? contOwn[l] : -1;
    rcv[l] = 0; __syncthreads();
    if (dA >= 0) rcv[dA] = 1;
    __syncthreads();
    {
      const unsigned long long recvM = __ballot(rcv[l] != 0);
      const unsigned long long dumm  = __ballot(dA < 0);
      if (dA < 0) dA = kthSetBit(~recvM, __popcll(dumm & ((1ull << l) - 1ull)));
    }
    __syncthreads();
    rcv[l] = 0; __syncthreads();
    if (dB >= 0) rcv[dB] = 1;
    __syncthreads();
    {
      const unsigned long long recvM = __ballot(rcv[l] != 0);
      const unsigned long long dumm  = __ballot(dB < 0);
      if (dB < 0) dB = kthSetBit(~recvM, __popcll(dumm & ((1ull << l) - 1ull)));
    }
    __syncthreads();
    // route rounds: owner -> canonical lane of its inter unit (parallel)
    int rA = (ownP[2*l]   >= 0) ? canonLane(50 + ownP[2*l])   : -1;
    int rB = (ownP[2*l+1] >= 0) ? canonLane(50 + ownP[2*l+1]) : -1;
    rcv[l] = 0; __syncthreads();
    if (rA >= 0) rcv[rA] = 1;           // distinct dests (canonLane is injective)
    __syncthreads();
    const int isRcvA = rcv[l];
    {
      const unsigned long long recvM = __ballot(isRcvA != 0);
      const unsigned long long dumm  = __ballot(rA < 0);
      if (rA < 0) rA = kthSetBit(~recvM, __popcll(dumm & ((1ull << l) - 1ull)));
    }
    __syncthreads();
    rcv[l] = 0; __syncthreads();
    if (rB >= 0) rcv[rB] = 1;
    __syncthreads();
    {
      const unsigned long long recvM = __ballot(rcv[l] != 0);
      const unsigned long long dumm  = __ballot(rB < 0);
      if (rB < 0) rB = kthSetBit(~recvM, __popcll(dumm & ((1ull << l) - 1ull)));
    }
    // meta words 10..21 (parallel)
    {
      int* M = meta + l * MSTRIDE;
      M[10] = dA * 4; M[11] = dB * 4;
      const float s1A = (splitRole[l] == 0) ? 1.f : 0.f, s1B = (splitRole[l] == 1) ? 1.f : 0.f;
      M[12] = __float_as_int(s1A); M[13] = __float_as_int(s1B);
      const float s2 = split2[l] ? 1.f : 0.f;
      M[14] = __float_as_int(s1A * s2); M[15] = __float_as_int(s1B * s2);
      M[16] = rA * 4; M[17] = rB * 4;
      M[18] = __float_as_int(isRcvA ? 1.f : 0.f);
      M[19] = __float_as_int(isRcvA ? 0.f : 1.f);
      const int pA = ownP[2*l], pB = ownP[2*l+1];
      M[20] = (pA >= 0) ? 50 + pA : 0;
      M[21] = (pB >= 0) ? 50 + pB : 0;
    }
    // zero + fill sensory tables (parallel)
    for (int t = l; t < CS*64; t += 64) {
      senP4[t] = make_float4(0.f,0.f,0.f,0.f); senP2[t] = make_float2(0.f,0.f); senAd[t] = 0;
    }
    __syncthreads();
    {
      const int E = off[64];
      for (int e = l; e < E; e += 64) {
        const int pre = ePre[e], pj = ePIdx[e];
        const int r  = e - off[pj];
        const int dd = deg[pj], f0 = pF0[pj], role0 = pRole[pj];
        const int take = dd < (CS - f0) ? dd : (CS - f0);
        int lane = pLane[pj], slot, role;
        if (r < take)            { slot = f0 + r;        role = role0; }
        else if (r < take + CS)  { lane += 1; slot = r - take;      role = 0; }
        else                     { lane += 2; slot = r - take - CS; role = 0; }
        if (lane > 63) lane = 63;
        const int col = 50 + pj;
        const int idx = pre * UNITS + col;
        const float sg = ssg[idx];
        const float nsgl = -sg * LOG2E, msl = smu[idx] * sg * LOG2E;
        const float wd = sw[idx], wn = wd * serev[idx];
        const int tt = slot * 64 + lane;
        senP4[tt] = make_float4(nsgl, msl, role ? 0.f : wn, role ? 0.f : wd);
        senP2[tt] = role ? make_float2(wn, wd) : make_float2(0.f, 0.f);
        senAd[tt] = pre * 4;
      }
    }
  }
}

// ---------------------------------------------------------------------------
// Run kernel: UNCHANGED from R4 (proven correct; one wave per batch element,
// owner registers + LDS mirror, static ds_permute merges, no atomics).
// ---------------------------------------------------------------------------
__global__ __launch_bounds__(64, 2) void ltc_run(
    const float* __restrict__ obs,     const float* __restrict__ hidden,
    const float* __restrict__ input_w, const float* __restrict__ input_b,
    const float* __restrict__ gleak,   const float* __restrict__ vleak,
    const float* __restrict__ cm,
    const float* __restrict__ q_w1, const float* __restrict__ q_b1,
    const float* __restrict__ q_w2, const float* __restrict__ q_b2,
    const float4* __restrict__ recP4, const float2* __restrict__ recP2,
    const int* __restrict__ recAd,
    const float4* __restrict__ senP4, const float2* __restrict__ senP2,
    const int* __restrict__ senAd,
    const int* __restrict__ meta, float* __restrict__ out, int B)
{
  const int l = threadIdx.x, b = blockIdx.x;
  __shared__ float mirror[256];   // [0..113] units, [128..255] scratch sinks
  char* mbase = (char*)mirror;

  float4 rp4[CR]; float2 rp2[CR]; int rad[CR];
#pragma unroll
  for (int s = 0; s < CR; ++s) { rp4[s] = recP4[s*64+l]; rp2[s] = recP2[s*64+l]; rad[s] = recAd[s*64+l]; }
  float4 sp4[CS]; float2 sp2[CS]; int sad[CS];
#pragma unroll
  for (int s = 0; s < CS; ++s) { sp4[s] = senP4[s*64+l]; sp2[s] = senP2[s*64+l]; sad[s] = senAd[s*64+l]; }

  const int* M = meta + l * MSTRIDE;
  const int   rPush1 = M[0], rPush2 = M[1];
  const float rS1A = __int_as_float(M[2]), rS1B = __int_as_float(M[3]);
  const float rS2A = __int_as_float(M[4]), rS2B = __int_as_float(M[5]);
  const int   rWrA = M[6], rWrB = M[7], rUA = M[8], rUB = M[9];
  const int   sPush1 = M[10], sPush2 = M[11];
  const float sS1A = __int_as_float(M[12]), sS1B = __int_as_float(M[13]);
  const float sS2A = __int_as_float(M[14]), sS2B = __int_as_float(M[15]);
  const int   sRtA = M[16], sRtB = M[17];
  const float sRndA = __int_as_float(M[18]), sRndB = __int_as_float(M[19]);
  const int   sUA = M[20], sUB = M[21];

  const float cmA  = cm[rUA]*6.f, glvA  = gleak[rUA]*vleak[rUA], cgA  = cm[rUA]*6.f + gleak[rUA] + EPS;
  const float cmB  = cm[rUB]*6.f, glvB  = gleak[rUB]*vleak[rUB], cgB  = cm[rUB]*6.f + gleak[rUB] + EPS;
  const float cmSA = cm[sUA]*6.f, glvSA = gleak[sUA]*vleak[sUA], cgSA = cm[sUA]*6.f + gleak[sUA] + EPS;
  const float cmSB = cm[sUB]*6.f, glvSB = gleak[sUB]*vleak[sUB], cgSB = cm[sUB]*6.f + gleak[sUB] + EPS;

  const int  iUnit = (l < 50) ? 64 + l : l;     // canonical inter unit of this lane
  const int  iWr   = iUnit * 4;
  float vIn = hidden[(size_t)b*UNITS + iUnit];
  float vPA = hidden[(size_t)b*UNITS + rUA];
  float vPB = hidden[(size_t)b*UNITS + rUB];

  mirror[l] = hidden[(size_t)b*UNITS + l];
  if (l < 50) mirror[64 + l] = hidden[(size_t)b*UNITS + 64 + l];

  const float iw = input_w[l], ibv = input_b[l];
  const float* ob = obs + (size_t)b*(TSTEPS*SDIM) + l;
  float xr = ob[0];

  for (int t = 0; t < TSTEPS; ++t) {
    const float xi = xr * iw + ibv;             // lane l holds obs dim l
    if (t + 1 < TSTEPS) xr = ob[(t + 1) * SDIM];

    // ---- sensory accumulation (balanced slots), merge, (aI,bI) route ----
    float snA=0.f, sdA=0.f, snB=0.f, sdB=0.f;
#pragma unroll
    for (int s = 0; s < CS; ++s) {
      const float sg = sigm(sp4[s].y, sp4[s].x, bperm(sad[s], xi));
      snA = fmaf(sp4[s].z, sg, snA); sdA = fmaf(sp4[s].w, sg, sdA);
      snB = fmaf(sp2[s].x, sg, snB); sdB = fmaf(sp2[s].y, sg, sdB);
    }
    { const float rn = dperm(sPush1, snA), rd = dperm(sPush1, sdA);
      snA = fmaf(sS1A, rn, snA); sdA = fmaf(sS1A, rd, sdA);
      snB = fmaf(sS1B, rn, snB); sdB = fmaf(sS1B, rd, sdB); }
    { const float rn = dperm(sPush2, snA), rd = dperm(sPush2, sdA);
      snA = fmaf(sS2A, rn, snA); sdA = fmaf(sS2A, rd, sdA);
      snB = fmaf(sS2B, rn, snB); sdB = fmaf(sS2B, rd, sdB); }
    const float rdA_ = __builtin_amdgcn_rcpf(cgSA + sdA);
    const float aA_ = cmSA * rdA_, bA_ = (glvSA + snA) * rdA_;
    const float rdB_ = __builtin_amdgcn_rcpf(cgSB + sdB);
    const float aB_ = cmSB * rdB_, bB_ = (glvSB + snB) * rdB_;
    const float ra1 = dperm(sRtA, aA_), rb1 = dperm(sRtA, bA_);
    const float ra2 = dperm(sRtB, aB_), rb2 = dperm(sRtB, bB_);
    const float aI = sRndA * ra1 + sRndB * ra2;
    const float bI = sRndA * rb1 + sRndB * rb2;

    // ---- 6 ODE unfolds ----
#pragma unroll 1
    for (int u = 0; u < 6; ++u) {
      wsync();                                   // prev writes -> this unfold's reads
      float nA=0.f, dA=0.f, nB=0.f, dB=0.f;
#pragma unroll
      for (int s = 0; s < CR; ++s) {
        const float pv = *(const float*)(mbase + rad[s]);
        const float sg = sigm(rp4[s].y, rp4[s].x, pv);
        nA = fmaf(rp4[s].z, sg, nA); dA = fmaf(rp4[s].w, sg, dA);
        nB = fmaf(rp2[s].x, sg, nB); dB = fmaf(rp2[s].y, sg, dB);
      }
      { const float rn = dperm(rPush1, nA), rd = dperm(rPush1, dA);
        nA = fmaf(rS1A, rn, nA); dA = fmaf(rS1A, rd, dA);
        nB = fmaf(rS1B, rn, nB); dB = fmaf(rS1B, rd, dB); }
      { const float rn = dperm(rPush2, nA), rd = dperm(rPush2, dA);
        nA = fmaf(rS2A, rn, nA); dA = fmaf(rS2A, rd, dA);
        nB = fmaf(rS2B, rn, nB); dB = fmaf(rS2B, rd, dB); }
      vPA = (fmaf(cmA, vPA, glvA) + nA) * __builtin_amdgcn_rcpf(cgA + dA);
      vPB = (fmaf(cmB, vPB, glvB) + nB) * __builtin_amdgcn_rcpf(cgB + dB);
      vIn = fmaf(aI, vIn, bI);
      wsync();                                   // all reads done -> overwrite
      *(float*)(mbase + rWrA) = vPA;
      *(float*)(mbase + rWrB) = vPB;
      *(float*)(mbase + iWr)  = vIn;
    }
  }
  wsync();

  // ---- outputs: h then Q head ----
  float* __restrict__ outH = out + (size_t)B * ACT;
  outH[(size_t)b*UNITS + l] = mirror[l];
  if (l < 50) outH[(size_t)b*UNITS + 64 + l] = mirror[64 + l];

  const int j2 = (l < 50) ? 64 + l : l;
  float h1 = q_b1[l], h2 = q_b1[j2];
  for (int i = 0; i < UNITS; ++i) {
    const float hv = mirror[i];
    h1 = fmaf(hv, q_w1[i*UNITS + l],  h1);
    h2 = fmaf(hv, q_w1[i*UNITS + j2], h2);
  }
  h1 = fmaxf(h1, 0.f); h2 = fmaxf(h2, 0.f);
  wsync();
  mirror[l] = h1;
  if (l < 50) mirror[64 + l] = h2;
  wsync();
  if (l < ACT) {
    float q = q_b2[l];
    for (int i = 0; i < UNITS; ++i) q = fmaf(mirror[i], q_w2[i*ACT + l], q);
    out[(size_t)b*ACT + l] = q;
  }
}

extern "C" void kernel_launch(void* const* d_in, const int* in_sizes, int n_in,
                              void* d_out, int out_size, void* d_ws, size_t ws_size,
                              hipStream_t stream)
{
  const float* obs           = (const float*)d_in[0];
  const float* hidden        = (const float*)d_in[1];
  const float* input_w       = (const float*)d_in[2];
  const float* input_b       = (const float*)d_in[3];
  const float* sensory_w     = (const float*)d_in[4];
  const float* sensory_mu    = (const float*)d_in[5];
  const float* sensory_sigma = (const float*)d_in[6];
  const float* sensory_erev  = (const float*)d_in[7];
  const float* sensory_mask  = (const float*)d_in[8];
  const float* w             = (const float*)d_in[9];
  const float* mu            = (const float*)d_in[10];
  const float* sigma         = (const float*)d_in[11];
  const float* erev          = (const float*)d_in[12];
  const float* mask          = (const float*)d_in[13];
  const float* gleak         = (const float*)d_in[14];
  const float* vleak         = (const float*)d_in[15];
  const float* cm            = (const float*)d_in[16];
  const float* q_w1          = (const float*)d_in[17];
  const float* q_b1          = (const float*)d_in[18];
  const float* q_w2          = (const float*)d_in[19];
  const float* q_b2          = (const float*)d_in[20];

  char* ws = (char*)d_ws;
  float4* recP4 = (float4*)(ws);            // 13*64*16 = 13312
  float2* recP2 = (float2*)(ws + 13312);    // 13*64*8  = 6656  -> 19968
  int*    recAd = (int*)   (ws + 19968);    // 13*64*4  = 3328  -> 23296
  float4* senP4 = (float4*)(ws + 23296);    // 9*64*16  = 9216  -> 32512
  float2* senP2 = (float2*)(ws + 32512);    // 9*64*8   = 4608  -> 37120
  int*    senAd = (int*)   (ws + 37120);    // 9*64*4   = 2304  -> 39424
  int*    meta  = (int*)   (ws + 39424);    // 64*24*4  = 6144  -> 45568

  build_all<<<2, 64, 0, stream>>>(
      w, mu, sigma, erev, mask,
      sensory_w, sensory_mu, sensory_sigma, sensory_erev, sensory_mask,
      recP4, recP2, recAd, senP4, senP2, senAd, meta);

  const int B = in_sizes[0] / (TSTEPS * SDIM);
  ltc_run<<<B, 64, 0, stream>>>(
      obs, hidden, input_w, input_b, gleak, vleak, cm,
      q_w1, q_b1, q_w2, q_b2,
      recP4, recP2, recAd, senP4, senP2, senAd, meta,
      (float*)d_out, B);
}